// Round 10
// baseline (156.608 us; speedup 1.0000x reference)
//
#include <hip/hip_runtime.h>
#include <hip/hip_bf16.h>

// B=8, H=W=32 (seq=1024), C=512, heads=8, head_dim=64, groups=32
#define SEQ   1024
#define CH    512
#define NHEAD 8
#define HDIM  64
#define BATCH 8

using short8   = __attribute__((ext_vector_type(8))) short;
using floatx4  = __attribute__((ext_vector_type(4))) float;
using floatx16 = __attribute__((ext_vector_type(16))) float;

__device__ inline unsigned short f2bf(float f) {
  __hip_bfloat16 h = __float2bfloat16(f);
  return __builtin_bit_cast(unsigned short, h);
}

// async 16B global->LDS DMA (lane-linear LDS dest required)
__device__ inline void load_lds16(const void* g, void* l) {
  __builtin_amdgcn_global_load_lds(
      (const __attribute__((address_space(1))) unsigned int*)g,
      (__attribute__((address_space(3))) unsigned int*)l, 16, 0, 0);
}

// ---------------------------------------------------------------------------
// K1a: GN partial stats (blocks 0..2047) + weight transposes (2048..3071).
// ---------------------------------------------------------------------------
__global__ __launch_bounds__(256) void prep_stats_kernel(
    const float* __restrict__ wqkv, const float* __restrict__ wout,
    const float* __restrict__ x,
    unsigned short* __restrict__ wqkvt, unsigned short* __restrict__ woutt,
    float2* __restrict__ stats) {
  __shared__ float SH[32 * 33 + 8];
  const int blk = blockIdx.x, tid = threadIdx.x;

  if (blk >= 2048) {
    const float* src; unsigned short* dst; int C, bx, by;
    if (blk < 2816) { int t = blk - 2048; src = wqkv; dst = wqkvt; C = 1536; bx = t % 48; by = t / 48; }
    else { int t = blk - 2816; src = wout; dst = woutt; C = 512; bx = t & 15; by = t >> 4; }
    float (*T)[33] = (float(*)[33])SH;
    int tx = tid & 31, ty = tid >> 5;
    for (int j = 0; j < 4; ++j)
      T[ty + j * 8][tx] = src[(size_t)(by * 32 + ty + j * 8) * C + bx * 32 + tx];
    __syncthreads();
    for (int j = 0; j < 4; ++j)
      dst[(size_t)(bx * 32 + ty + j * 8) * 512 + by * 32 + tx] = f2bf(T[tx][ty + j * 8]);
    return;
  }

  const int bg = blk >> 3, chunk = blk & 7;
  const int b = bg >> 5, g = bg & 31;
  const size_t base = (size_t)b * SEQ * CH + (size_t)chunk * 128 * CH + g * 16;

  float s = 0.f, sq = 0.f;
  for (int i = 0; i < 2; ++i) {
    int c = i * 256 + tid;
    int r = c >> 2, c4 = (c & 3) * 4;
    float4 v = *(const float4*)(x + base + (size_t)r * CH + c4);
    s  += v.x + v.y + v.z + v.w;
    sq += v.x * v.x + v.y * v.y + v.z * v.z + v.w * v.w;
  }
  for (int off = 1; off < 64; off <<= 1) {
    s  += __shfl_xor(s, off);
    sq += __shfl_xor(sq, off);
  }
  float* ls = SH + 1056;
  float* lq = SH + 1060;
  int wid = tid >> 6, lane = tid & 63;
  if (lane == 0) { ls[wid] = s; lq[wid] = sq; }
  __syncthreads();
  if (tid == 0) {
    float2 p;
    p.x = ls[0] + ls[1] + ls[2] + ls[3];
    p.y = lq[0] + lq[1] + lq[2] + lq[3];
    stats[(bg << 3) + chunk] = p;
  }
}

// ---------------------------------------------------------------------------
// K1b: GN apply.
// ---------------------------------------------------------------------------
__global__ __launch_bounds__(256) void prep_apply_kernel(
    const float* __restrict__ x, const float* __restrict__ gsc,
    const float* __restrict__ gbs, const float2* __restrict__ stats,
    unsigned short* __restrict__ xn) {
  const int blk = blockIdx.x, tid = threadIdx.x;
  const int bg = blk >> 3, chunk = blk & 7;
  const int b = bg >> 5, g = bg & 31;

  float ts = 0.f, tq = 0.f;
  for (int i = 0; i < 8; ++i) {
    float2 p = stats[(bg << 3) + i];
    ts += p.x; tq += p.y;
  }
  const float inv_n = 1.0f / 16384.0f;
  float mean = ts * inv_n;
  float var  = tq * inv_n - mean * mean;
  float rstd = rsqrtf(var + 1e-6f);

  const size_t base = (size_t)b * SEQ * CH + (size_t)chunk * 128 * CH + g * 16;
  int c4 = (tid & 3) * 4;
  float4 sc = *(const float4*)(gsc + g * 16 + c4);
  float4 bs = *(const float4*)(gbs + g * 16 + c4);
  for (int i = 0; i < 2; ++i) {
    int c = i * 256 + tid;
    int r = c >> 2;
    float4 v = *(const float4*)(x + base + (size_t)r * CH + c4);
    ushort4 o;
    o.x = f2bf((v.x - mean) * rstd * sc.x + bs.x);
    o.y = f2bf((v.y - mean) * rstd * sc.y + bs.y);
    o.z = f2bf((v.z - mean) * rstd * sc.z + bs.z);
    o.w = f2bf((v.w - mean) * rstd * sc.w + bs.w);
    *(ushort4*)(xn + base + (size_t)r * CH + c4) = o;
  }
}

// ---------------------------------------------------------------------------
// K2/K4: GEMM C = A(MxK) * Bt(NxK)^T, bf16 in, fp32 acc, MTILE x 128 tile.
// EPI 0 (MTILE=128, QKV): +bias; q scaled (1/64)*log2e; q/k -> (h,s,d);
//     v -> transposed vt (h,d,s) with s-bits 2,3 SWAPPED within 16-blocks so
//     attn's 32x32 PV consumes softmaxed C-regs directly as A-operands.
// EPI 1 (MTILE=64, out):  +bias +residual, fp32 out.
// ---------------------------------------------------------------------------
template <int EPI, int MTILE>
__global__ __launch_bounds__(256) void gemm_bt_kernel(
    const unsigned short* __restrict__ A, const unsigned short* __restrict__ Bt,
    int K, int N,
    const float* __restrict__ bias, const float* __restrict__ resid,
    float* __restrict__ outf,
    unsigned short* __restrict__ qb, unsigned short* __restrict__ kb,
    unsigned short* __restrict__ vtb) {
  constexpr int SMSZ = (MTILE == 128) ? 17408 : 16896;
  constexpr int NI   = (MTILE == 128) ? 4 : 2;
  __shared__ alignas(16) unsigned short SM[SMSZ];
  unsigned short* LA = SM;                 // MTILE x 64, swizzled
  unsigned short* LB = SM + MTILE * 64;    // 128 x 64, swizzled

  const int tid = threadIdx.x;
  const int wid = tid >> 6, lane = tid & 63;
  const int quad = lane >> 4, m16 = lane & 15;
  const int sw = m16 & 7;
  const int wm = (MTILE == 128) ? (wid & 1) * 64 : 0;
  const int wn = (MTILE == 128) ? (wid >> 1) * 64 : wid * 32;
  const int m0 = blockIdx.x * MTILE, n0 = blockIdx.y * 128;

  floatx4 acc[4][NI];
  for (int i = 0; i < 4; ++i)
    for (int j = 0; j < NI; ++j) acc[i][j] = 0.f;

  for (int k0 = 0; k0 < K; k0 += 64) {
    for (int i = 0; i < MTILE / 32; ++i) {
      int c = i * 256 + tid;
      int r = c >> 3, kc = c & 7;
      load_lds16(A + (size_t)(m0 + r) * K + k0 + ((kc ^ (r & 7)) << 3), &LA[c << 3]);
    }
    for (int i = 0; i < 4; ++i) {
      int c = i * 256 + tid;
      int r = c >> 3, kc = c & 7;
      load_lds16(Bt + (size_t)(n0 + r) * K + k0 + ((kc ^ (r & 7)) << 3), &LB[c << 3]);
    }
    __syncthreads();
    for (int kq = 0; kq < 2; ++kq) {
      int csw = (((kq << 2) + quad) ^ sw) << 3;
      short8 af[4], bf[NI];
      for (int mi = 0; mi < 4; ++mi)
        af[mi] = *(const short8*)&LA[(wm + mi * 16 + m16) * 64 + csw];
      for (int ni = 0; ni < NI; ++ni)
        bf[ni] = *(const short8*)&LB[(wn + ni * 16 + m16) * 64 + csw];
      for (int mi = 0; mi < 4; ++mi)
        for (int ni = 0; ni < NI; ++ni)
          acc[mi][ni] = __builtin_amdgcn_mfma_f32_16x16x32_bf16(af[mi], bf[ni], acc[mi][ni], 0, 0, 0);
    }
    __syncthreads();
  }

  // C/D layout: row = quad*4+reg, col = lane&15
  const int b = m0 >> 10;
  if (EPI == 0) {
    const int part = n0 >> 9;                // 0=q 1=k 2=v (block-uniform)
    if (part < 2) {
      const float qscale = (part == 0) ? 0.0225421381f : 1.0f;  // (1/64)*log2e
      unsigned short* dst = (part == 0) ? qb : kb;
      for (int mi = 0; mi < 4; ++mi)
        for (int ni = 0; ni < 4; ++ni) {
          int ln = wn + ni * 16 + m16;
          float bb = bias[n0 + ln];
          for (int reg = 0; reg < 4; ++reg)
            SM[(wm + mi * 16 + quad * 4 + reg) * 136 + ln] =
                f2bf((acc[mi][ni][reg] + bb) * qscale);
        }
      __syncthreads();
      const int colb = n0 & 511;
      for (int j = 0; j < 8; ++j) {
        int c = j * 256 + tid;               // 2048 16B chunks
        int m = c >> 4, n8 = (c & 15) * 8;
        int h = (colb + n8) >> 6, d = n8 & 63;
        int sp = (m0 & 1023) + m;
        int4 v = *(const int4*)&SM[m * 136 + n8];
        *(int4*)(dst + (((size_t)(b * NHEAD + h)) * SEQ + sp) * HDIM + d) = v;
      }
    } else {
      // v: transpose [n][m]; s-index bits 2,3 swapped (quad -> qswap) for
      // attn's 32x32 PV A-operand consumption
      const int qswap = ((quad & 1) << 1) | (quad >> 1);
      for (int mi = 0; mi < 4; ++mi)
        for (int ni = 0; ni < 4; ++ni) {
          int ln = wn + ni * 16 + m16;
          float bb = bias[n0 + ln];
          int sbase = wm + mi * 16 + qswap * 4;
          for (int reg = 0; reg < 4; ++reg)
            SM[ln * 136 + sbase + reg] = f2bf(acc[mi][ni][reg] + bb);
        }
      __syncthreads();
      int hbase = (n0 - 1024) >> 6;
      for (int j = 0; j < 8; ++j) {
        int c = j * 256 + tid;
        int ld = c >> 4, sp8 = (c & 15) * 8;
        int h = hbase + (ld >> 6), d = ld & 63;
        int4 v = *(const int4*)&SM[ld * 136 + sp8];
        *(int4*)(vtb + ((size_t)(b * NHEAD + h) * HDIM + d) * SEQ + (m0 & 1023) + sp8) = v;
      }
    }
  } else {
    float* SMf = (float*)SM;                 // 64 x 132 fp32
    for (int mi = 0; mi < 4; ++mi)
      for (int ni = 0; ni < NI; ++ni) {
        int ln = wn + ni * 16 + m16;
        float bb = bias[n0 + ln];
        for (int reg = 0; reg < 4; ++reg)
          SMf[(mi * 16 + quad * 4 + reg) * 132 + ln] = acc[mi][ni][reg] + bb;
      }
    __syncthreads();
    for (int j = 0; j < 8; ++j) {
      int c = j * 256 + tid;                 // 2048 float4 chunks
      int m = c >> 5, n4 = (c & 31) * 4;
      size_t idx = (size_t)(m0 + m) * N + n0 + n4;
      float4 v = *(const float4*)&SMf[m * 132 + n4];
      float4 rr = *(const float4*)&resid[idx];
      v.x += rr.x; v.y += rr.y; v.z += rr.z; v.w += rr.w;
      *(float4*)&outf[idx] = v;
    }
  }
}

// ---------------------------------------------------------------------------
// K3: flash attention with 32x32x16 MFMA.  512 thr, 8 waves x 32 q = 256-row
// q-tile; grid 64 heads x 4 qt = 256 blocks (1/CU, 8 waves).  64-s kt tiles,
// DOUBLE-buffered DMA (1 block/CU -> no inter-block overlap to lean on).
// Padded 9-chunk LDS rows give uniform bank groups for 32-row fragments
// (pad chunk staged as duplicate to keep DMA lane-linear).  Max-free exp2
// softmax; St C-regs feed PV A-operands directly (V has s-bits 2,3 swapped).
// ---------------------------------------------------------------------------
__global__ __launch_bounds__(512) void attn_kernel(
    const unsigned short* __restrict__ qb, const unsigned short* __restrict__ kb,
    const unsigned short* __restrict__ vtb, unsigned short* __restrict__ ao) {
  const int head = blockIdx.x, qt = blockIdx.y;
  const int b = head >> 3, h = head & 7;
  const int tid = threadIdx.x;
  const int wid = tid >> 6, lane = tid & 63;
  const int l31 = lane & 31, half = lane >> 5;

  __shared__ alignas(16) unsigned short sK[2][64 * 72];  // 64 s x 64 d, 9-chunk rows
  __shared__ alignas(16) unsigned short sV[2][64 * 72];  // 64 d x 64 s, 9-chunk rows

  const unsigned short* kbase = kb  + (size_t)head * SEQ * HDIM;
  const unsigned short* vbase = vtb + (size_t)head * HDIM * SEQ;

  auto stage = [&](int kt, int bf) {
    {
      int c = tid;                              // 512 of 576 chunks
      int r = c / 9, kc = c - r * 9;
      int col = (kc == 8) ? 0 : kc;
      load_lds16(kbase + (size_t)(kt * 64 + r) * HDIM + col * 8, &sK[bf][c * 8]);
      load_lds16(vbase + (size_t)r * SEQ + kt * 64 + col * 8, &sV[bf][c * 8]);
    }
    if (tid < 64) {
      int c = 512 + tid;
      int r = c / 9, kc = c - r * 9;
      int col = (kc == 8) ? 0 : kc;
      load_lds16(kbase + (size_t)(kt * 64 + r) * HDIM + col * 8, &sK[bf][c * 8]);
      load_lds16(vbase + (size_t)r * SEQ + kt * 64 + col * 8, &sV[bf][c * 8]);
    }
  };

  // Q B-frags: lane q = l31, k(d) = dstep*16 + half*8 + j (pre-scaled upstream)
  const size_t qrow = (size_t)head * SEQ + qt * 256 + wid * 32 + l31;
  short8 qf[4];
  for (int dstep = 0; dstep < 4; ++dstep)
    qf[dstep] = *(const short8*)(qb + qrow * HDIM + dstep * 16 + half * 8);

  float lacc = 0.f;
  floatx16 o0 = 0.f, o1 = 0.f;   // d 0..31 / 32..63

  stage(0, 0);
  for (int kt = 0; kt < 16; ++kt) {
    const int bf = kt & 1;
    __syncthreads();
    if (kt < 15) stage(kt + 1, bf ^ 1);

    for (int sf = 0; sf < 2; ++sf) {
      // St[s][q] = K*Q^T over d=64 (4 MFMA); A = K rows (m=s), B = Q (n=q)
      floatx16 st = 0.f;
      const unsigned short* kr = &sK[bf][(sf * 32 + l31) * 72 + half * 8];
      for (int dstep = 0; dstep < 4; ++dstep)
        st = __builtin_amdgcn_mfma_f32_32x32x16_bf16(
            *(const short8*)(kr + dstep * 16), qf[dstep], st, 0, 0, 0);

      // exp2 + pack: C-regs [0..7] -> pf0 (k-step 0), [8..15] -> pf1 (step 1)
      short8 pf0, pf1;
      for (int j = 0; j < 8; ++j) {
        float p0 = exp2f(st[j]);
        float p1 = exp2f(st[8 + j]);
        lacc += p0 + p1;
        pf0[j] = (short)f2bf(p0);
        pf1[j] = (short)f2bf(p1);
      }

      // O += P*V  (B = permuted-Vt rows; chunk = sf*4 + t*2 + half)
      const unsigned short* vr0 = &sV[bf][l31 * 72];
      const unsigned short* vr1 = &sV[bf][(32 + l31) * 72];
      int c0 = (sf * 4 + half) * 8;
      int c1 = (sf * 4 + 2 + half) * 8;
      o0 = __builtin_amdgcn_mfma_f32_32x32x16_bf16(pf0, *(const short8*)(vr0 + c0), o0, 0, 0, 0);
      o1 = __builtin_amdgcn_mfma_f32_32x32x16_bf16(pf0, *(const short8*)(vr1 + c0), o1, 0, 0, 0);
      o0 = __builtin_amdgcn_mfma_f32_32x32x16_bf16(pf1, *(const short8*)(vr0 + c1), o0, 0, 0, 0);
      o1 = __builtin_amdgcn_mfma_f32_32x32x16_bf16(pf1, *(const short8*)(vr1 + c1), o1, 0, 0, 0);
    }
  }

  // denominator: lane holds partial for q=l31; combine halves, then broadcast
  lacc += __shfl_xor(lacc, 32);
  float linv = 1.0f / lacc;

  // O C-layout: col(d)=l31, row(q) = (reg&3) + 8*(reg>>2) + 4*half
  const int qg0 = qt * 256 + wid * 32;
  for (int pr = 0; pr < 4; ++pr)
    for (int i = 0; i < 4; ++i) {
      int reg = pr * 4 + i;
      int ql = i + half * 4 + pr * 8;
      float lr = __shfl(linv, ql);
      size_t base = (size_t)(b * SEQ + qg0 + ql) * CH + h * HDIM;
      ao[base + l31]      = f2bf(o0[reg] * lr);
      ao[base + 32 + l31] = f2bf(o1[reg] * lr);
    }
}

// ---------------------------------------------------------------------------
extern "C" void kernel_launch(void* const* d_in, const int* in_sizes, int n_in,
                              void* d_out, int out_size, void* d_ws, size_t ws_size,
                              hipStream_t stream) {
  const float* x    = (const float*)d_in[0];
  const float* gsc  = (const float*)d_in[1];
  const float* gbs  = (const float*)d_in[2];
  const float* wqkv = (const float*)d_in[3];
  const float* bqkv = (const float*)d_in[4];
  const float* wout = (const float*)d_in[5];
  const float* bout = (const float*)d_in[6];
  float* out = (float*)d_out;

  char* ws = (char*)d_ws;
  unsigned short* xn    = (unsigned short*)(ws);                 // 8 MB (8192x512)
  unsigned short* wqkvt = (unsigned short*)(ws + 8388608);       // 1.5 MB (1536x512)
  unsigned short* woutt = (unsigned short*)(ws + 9961472);       // 0.5 MB (512x512)
  unsigned short* qb    = (unsigned short*)(ws + 10485760);      // 8 MB (64,1024,64)
  unsigned short* kb    = (unsigned short*)(ws + 18874368);      // 8 MB (64,1024,64)
  unsigned short* vtb   = (unsigned short*)(ws + 27262976);      // 8 MB (64,64,1024)
  unsigned short* ao    = (unsigned short*)(ws + 35651584);      // 8 MB (8192x512)
  float2*         stats = (float2*)(ws + 44040192);              // 16 KB

  prep_stats_kernel<<<3072, 256, 0, stream>>>(wqkv, wout, x, wqkvt, woutt, stats);
  prep_apply_kernel<<<2048, 256, 0, stream>>>(x, gsc, gbs, stats, xn);
  gemm_bt_kernel<0, 128><<<dim3(64, 12), 256, 0, stream>>>(
      xn, wqkvt, 512, 1536, bqkv, nullptr, nullptr, qb, kb, vtb);
  attn_kernel<<<dim3(64, 4), 512, 0, stream>>>(qb, kb, vtb, ao);
  gemm_bt_kernel<1, 64><<<dim3(128, 4), 256, 0, stream>>>(
      ao, woutt, 512, 512, bout, x, out, nullptr, nullptr, nullptr);
}